// Round 1
// baseline (422.871 us; speedup 1.0000x reference)
//
#include <hip/hip_runtime.h>

#define NT 65536
#define MD 1024
#define NE 64
#define TB 128                 // tokens per gate block (4 waves x 32 tokens)
#define NGATE (NT / TB)        // 512 gate blocks
#define NGRP (NT / 64)         // 1024 rank groups of 64 tokens

typedef short bf16x8 __attribute__((ext_vector_type(8)));
typedef float f32x4  __attribute__((ext_vector_type(4)));

// Exact 3-way bf16 split: f == h + m + l (truncation split, zero error).
__device__ __forceinline__ void split1(float f, ushort& h, ushort& m, ushort& lo) {
    unsigned u  = __float_as_uint(f);
    unsigned hb = u & 0xFFFF0000u;
    float    r1 = f - __uint_as_float(hb);
    unsigned mb = __float_as_uint(r1) & 0xFFFF0000u;
    float    r2 = r1 - __uint_as_float(mb);       // <= 8 significant bits: exact bf16
    h  = (ushort)(hb >> 16);
    m  = (ushort)(mb >> 16);
    lo = (ushort)(__float_as_uint(r2) >> 16);
}

__device__ __forceinline__ void split8(const float4 a, const float4 b,
                                       bf16x8& h, bf16x8& m, bf16x8& lo) {
    float f[8] = {a.x, a.y, a.z, a.w, b.x, b.y, b.z, b.w};
#pragma unroll
    for (int j = 0; j < 8; ++j) {
        ushort hh, mm, ll;
        split1(f[j], hh, mm, ll);
        h[j] = (short)hh; m[j] = (short)mm; lo[j] = (short)ll;
    }
}

// ---------------------------------------------------------------------------
// Kernel 0: split wg into 3 bf16 planes laid out in MFMA-B-fragment order:
// wgp[s][c][nt][lane][j]  (s: split, c: k-chunk of 32, nt: 16-expert tile)
// lane j holds wg[nt*16 + (lane&15)][c*32 + (lane>>4)*8 + j].
// ---------------------------------------------------------------------------
__global__ __launch_bounds__(256) void prep_kernel(
    const float* __restrict__ wg, ushort* __restrict__ wgp)
{
    const int idx = blockIdx.x * 256 + threadIdx.x;   // 0..8191
    const int l  = idx & 63;
    const int nt = (idx >> 6) & 3;
    const int c  = idx >> 8;
    const int e  = nt * 16 + (l & 15);
    const int k0 = c * 32 + (l >> 4) * 8;
    const float* src = wg + (size_t)e * MD + k0;
    float4 a = *(const float4*)(src);
    float4 b = *(const float4*)(src + 4);
    bf16x8 h, m, lo;
    split8(a, b, h, m, lo);
    *(bf16x8*)(wgp + (size_t)idx * 8)          = h;
    *(bf16x8*)(wgp + 65536 + (size_t)idx * 8)  = m;
    *(bf16x8*)(wgp + 131072 + (size_t)idx * 8) = lo;
}

// 6-product split-bf16 MFMA accumulate (drops only ml/lm/ll ~2^-23 terms)
#define MFMA6(accv, xh, xm, xl, wh, wm, wl)                                        \
    accv = __builtin_amdgcn_mfma_f32_16x16x32_bf16(xh, wh, accv, 0, 0, 0);         \
    accv = __builtin_amdgcn_mfma_f32_16x16x32_bf16(xh, wm, accv, 0, 0, 0);         \
    accv = __builtin_amdgcn_mfma_f32_16x16x32_bf16(xm, wh, accv, 0, 0, 0);         \
    accv = __builtin_amdgcn_mfma_f32_16x16x32_bf16(xm, wm, accv, 0, 0, 0);         \
    accv = __builtin_amdgcn_mfma_f32_16x16x32_bf16(xh, wl, accv, 0, 0, 0);         \
    accv = __builtin_amdgcn_mfma_f32_16x16x32_bf16(xl, wh, accv, 0, 0, 0);

// ---------------------------------------------------------------------------
// Kernel 1: MFMA gating GEMM + argmax + softmax + rank/hist + me accumulation.
// 128 tokens/block, 4 waves, each wave: 32 tokens x 64 experts (2x4 fragments).
// x: global->reg (each byte read once, 1-chunk prefetch). wg: L2-resident
// fragment-ordered planes, lane-contiguous loads. No LDS/barrier in K-loop.
// ---------------------------------------------------------------------------
__global__ __launch_bounds__(256, 2) void gate_kernel(
    const float* __restrict__ x, const ushort* __restrict__ wgp,
    float* __restrict__ out, unsigned* __restrict__ packed_ws,
    int* __restrict__ hist_ws, float* __restrict__ me)
{
    __shared__ float lt[TB * 65];   // logits tile, stride 65: conflict-free rows
    __shared__ float inv[TB];

    const int tid = threadIdx.x;
    const int wv  = tid >> 6;
    const int l   = tid & 63;
    const int lr  = l & 15;          // fragment row (token) / col (expert)
    const int lg  = l >> 4;          // k-group within fragment
    const int t0  = blockIdx.x * TB + wv * 32;

    const float*  xa0 = x + (size_t)(t0 + lr) * MD + lg * 8;   // m-tile 0
    const float*  xa1 = xa0 + 16 * MD;                          // m-tile 1
    const ushort* wbh = wgp + (size_t)l * 8;
    const ushort* wbm = wbh + 65536;
    const ushort* wbl = wbh + 131072;

    f32x4 acc[2][4];
#pragma unroll
    for (int mt = 0; mt < 2; ++mt)
#pragma unroll
        for (int nt = 0; nt < 4; ++nt) acc[mt][nt] = f32x4{0.f, 0.f, 0.f, 0.f};

    float4 a00 = *(const float4*)(xa0);
    float4 a01 = *(const float4*)(xa0 + 4);
    float4 a10 = *(const float4*)(xa1);
    float4 a11 = *(const float4*)(xa1 + 4);

#pragma unroll 2
    for (int c = 0; c < 32; ++c) {
        const ushort* ph = wbh + c * 2048;
        const ushort* pm = wbm + c * 2048;
        const ushort* pl = wbl + c * 2048;
        bf16x8 bh[4], bm_[4], bl[4];
#pragma unroll
        for (int nt = 0; nt < 4; ++nt) {
            bh[nt]  = *(const bf16x8*)(ph + nt * 512);
            bm_[nt] = *(const bf16x8*)(pm + nt * 512);
            bl[nt]  = *(const bf16x8*)(pl + nt * 512);
        }
        float4 c00 = a00, c01 = a01, c10 = a10, c11 = a11;
        if (c < 31) {                       // prefetch next chunk's x
            const float* xn0 = xa0 + (c + 1) * 32;
            const float* xn1 = xa1 + (c + 1) * 32;
            a00 = *(const float4*)(xn0);
            a01 = *(const float4*)(xn0 + 4);
            a10 = *(const float4*)(xn1);
            a11 = *(const float4*)(xn1 + 4);
        }
        bf16x8 ah0, am0, al0, ah1, am1, al1;
        split8(c00, c01, ah0, am0, al0);
        split8(c10, c11, ah1, am1, al1);
#pragma unroll
        for (int nt = 0; nt < 4; ++nt) {
            MFMA6(acc[0][nt], ah0, am0, al0, bh[nt], bm_[nt], bl[nt]);
            MFMA6(acc[1][nt], ah1, am1, al1, bh[nt], bm_[nt], bl[nt]);
        }
    }

    // ---- epilogue: C/D layout col=lane&15, row=(lane>>4)*4+reg [m89] ----
#pragma unroll
    for (int mt = 0; mt < 2; ++mt)
#pragma unroll
        for (int nt = 0; nt < 4; ++nt)
#pragma unroll
            for (int r = 0; r < 4; ++r)
                lt[(wv * 32 + mt * 16 + lg * 4 + r) * 65 + nt * 16 + lr] =
                    acc[mt][nt][r];
    __syncthreads();

    if (tid < 128) {
        const int grp = tid >> 6;        // 64-token group within block
        const int t   = tid & 63;        // token within group == lane id
        float* row = &lt[(grp * 64 + t) * 65];
        float mx = -1e30f; int am = 0;
        for (int e = 0; e < NE; ++e) {
            float v = row[e];
            if (v > mx) { mx = v; am = e; }     // strict >: first-max argmax
        }
        float s = 0.f;
        for (int e = 0; e < NE; ++e) {
            float ev = __expf(row[e] - mx);
            row[e] = ev;
            s += ev;
        }
        float g = 1.0f / s;
        const int gt = blockIdx.x * TB + grp * 64 + t;
        out[1 + gt] = (float)am;             // indices1_s
        out[2 + 2 * NT + gt] = g;            // gates1_s (exp at max == 1)
        inv[grp * 64 + t] = g;

        const unsigned long long below = (1ull << t) - 1ull;
        int rank = 0, mycnt = 0;
        for (int e = 0; e < NE; ++e) {
            unsigned long long msk = __ballot(am == e);
            if (t == e)  mycnt = (int)__popcll(msk);
            if (am == e) rank  = (int)__popcll(msk & below);
        }
        packed_ws[gt] = (unsigned)am | ((unsigned)rank << 8);
        hist_ws[(blockIdx.x * 2 + grp) * NE + t] = mycnt;
    }
    __syncthreads();

    if (tid < 128) {                       // me partial: 2 waves, 64 tokens each
        const int grp = tid >> 6;
        const int e   = tid & 63;
        const float* base = &lt[grp * 64 * 65];
        const float* iv   = &inv[grp * 64];
        float s = 0.f;
        for (int t = 0; t < 64; ++t) s += base[t * 65 + e] * iv[t];
        atomicAdd(&me[e], s);
    }
}

// ---------------------------------------------------------------------------
// Kernel 2: per-expert exclusive scan over the 1024 group histograms
// (in-place: hist_ws becomes group offsets). Also emits ce[e] = total.
// ---------------------------------------------------------------------------
__global__ __launch_bounds__(256) void scan_kernel(
    int* __restrict__ hist_ws, float* __restrict__ ce)
{
    const int e = blockIdx.x;
    const int tid = threadIdx.x;
    const int lane = tid & 63, wave = tid >> 6;
    __shared__ int wtot[4];

    int h[4];
#pragma unroll
    for (int j = 0; j < 4; ++j) h[j] = hist_ws[(tid * 4 + j) * NE + e];
    int s = h[0] + h[1] + h[2] + h[3];

    int scan = s;
#pragma unroll
    for (int d = 1; d < 64; d <<= 1) {
        int o = __shfl_up(scan, d, 64);
        if (lane >= d) scan += o;
    }
    if (lane == 63) wtot[wave] = scan;
    __syncthreads();
    int wpre = 0;
#pragma unroll
    for (int w = 0; w < 4; ++w)
        if (w < wave) wpre += wtot[w];

    int run = wpre + scan - s;
#pragma unroll
    for (int j = 0; j < 4; ++j) {
        hist_ws[(tid * 4 + j) * NE + e] = run;
        run += h[j];
    }
    if (tid == 255) ce[e] = (float)run;
}

// ---------------------------------------------------------------------------
// Kernel 3: locations1_s + (block 0) l_aux & scalar outputs (finalize folded).
// ---------------------------------------------------------------------------
__global__ __launch_bounds__(256) void emit_kernel(
    const unsigned* __restrict__ packed_ws, const int* __restrict__ offs_ws,
    const float* __restrict__ me, const float* __restrict__ ce,
    float* __restrict__ out)
{
    const int i = blockIdx.x * 256 + threadIdx.x;
    const unsigned p = packed_ws[i];
    const int am = (int)(p & 63u);
    const int rank = (int)(p >> 8);
    const int b = i >> 6;
    out[2 + NT + i] = (float)(offs_ws[b * NE + am] + rank);

    if (blockIdx.x == 0 && threadIdx.x < 64) {
        float v = me[threadIdx.x] * ce[threadIdx.x];
#pragma unroll
        for (int d = 32; d > 0; d >>= 1) v += __shfl_down(v, d, 64);
        if (threadIdx.x == 0) {
            out[0] = v * (float)((double)NE / ((double)NT * (double)NT));
            out[1 + NT] = 1024.0f;      // capacity = ceil(N/E) * 1.0
            out[2 + 3 * NT] = 64.0f;    // E
        }
    }
}

extern "C" void kernel_launch(void* const* d_in, const int* in_sizes, int n_in,
                              void* d_out, int out_size, void* d_ws, size_t ws_size,
                              hipStream_t stream)
{
    const float* x  = (const float*)d_in[0];
    const float* wg = (const float*)d_in[1];
    float* out = (float*)d_out;

    unsigned* packed_ws = (unsigned*)d_ws;                          // 256 KB
    int*      hist_ws   = (int*)((char*)d_ws + 262144);             // 256 KB
    float*    me        = (float*)((char*)d_ws + 524288);           // 256 B
    float*    ce        = (float*)((char*)d_ws + 524544);           // 256 B
    ushort*   wgp       = (ushort*)((char*)d_ws + 524800);          // 384 KB, 16B-aligned

    hipMemsetAsync(me, 0, NE * sizeof(float), stream);
    prep_kernel<<<32, 256, 0, stream>>>(wg, wgp);
    gate_kernel<<<NGATE, 256, 0, stream>>>(x, wgp, out, packed_ws, hist_ws, me);
    scan_kernel<<<NE, 256, 0, stream>>>(hist_ws, ce);
    emit_kernel<<<NT / 256, 256, 0, stream>>>(packed_ws, hist_ws, me, ce, out);
}

// Round 3
// 399.652 us; speedup vs baseline: 1.0581x; 1.0581x over previous
//
#include <hip/hip_runtime.h>

#define NT 65536
#define MD 1024
#define NE 64
#define TB 128                 // tokens per gate block (4 token-groups x 32)
#define NGATE (NT / TB)        // 512 gate blocks

typedef short bf16x8 __attribute__((ext_vector_type(8)));
typedef float f32x4  __attribute__((ext_vector_type(4)));

// Exact 3-way bf16 split: f == h + m + l (truncation split, zero error).
__device__ __forceinline__ void split1(float f, ushort& h, ushort& m, ushort& lo) {
    unsigned u  = __float_as_uint(f);
    unsigned hb = u & 0xFFFF0000u;
    float    r1 = f - __uint_as_float(hb);
    unsigned mb = __float_as_uint(r1) & 0xFFFF0000u;
    float    r2 = r1 - __uint_as_float(mb);       // <= 8 significant bits: exact bf16
    h  = (ushort)(hb >> 16);
    m  = (ushort)(mb >> 16);
    lo = (ushort)(__float_as_uint(r2) >> 16);
}

__device__ __forceinline__ void split8(const float4 a, const float4 b,
                                       bf16x8& h, bf16x8& m, bf16x8& lo) {
    float f[8] = {a.x, a.y, a.z, a.w, b.x, b.y, b.z, b.w};
#pragma unroll
    for (int j = 0; j < 8; ++j) {
        ushort hh, mm, ll;
        split1(f[j], hh, mm, ll);
        h[j] = (short)hh; m[j] = (short)mm; lo[j] = (short)ll;
    }
}

// ---------------------------------------------------------------------------
// Kernel 0: split wg into 3 bf16 planes laid out in MFMA-B-fragment order:
// wgp[s][c][nt][lane][j]  (s: split plane, c: k-chunk of 32, nt: 16-expert tile)
// elem idx = ((c*4+nt)*64 + lane)*8 + j, plane stride 65536 elements.
// Also zeroes me[] (replaces the hipMemsetAsync dispatch).
// ---------------------------------------------------------------------------
__global__ __launch_bounds__(256) void prep_kernel(
    const float* __restrict__ wg, ushort* __restrict__ wgp,
    float* __restrict__ me)
{
    const int idx = blockIdx.x * 256 + threadIdx.x;   // 0..8191
    if (blockIdx.x == 0 && threadIdx.x < NE) me[threadIdx.x] = 0.f;
    const int l  = idx & 63;
    const int nt = (idx >> 6) & 3;
    const int c  = idx >> 8;
    const int e  = nt * 16 + (l & 15);
    const int k0 = c * 32 + (l >> 4) * 8;
    const float* src = wg + (size_t)e * MD + k0;
    float4 a = *(const float4*)(src);
    float4 b = *(const float4*)(src + 4);
    bf16x8 h, m, lo;
    split8(a, b, h, m, lo);
    *(bf16x8*)(wgp + (size_t)idx * 8)          = h;
    *(bf16x8*)(wgp + 65536 + (size_t)idx * 8)  = m;
    *(bf16x8*)(wgp + 131072 + (size_t)idx * 8) = lo;
}

// 6-product split-bf16 MFMA accumulate (drops only ml/lm/ll ~2^-23 terms)
#define MFMA6(accv, xh, xm, xl, wh, wm, wl)                                        \
    accv = __builtin_amdgcn_mfma_f32_16x16x32_bf16(xh, wh, accv, 0, 0, 0);         \
    accv = __builtin_amdgcn_mfma_f32_16x16x32_bf16(xh, wm, accv, 0, 0, 0);         \
    accv = __builtin_amdgcn_mfma_f32_16x16x32_bf16(xm, wh, accv, 0, 0, 0);         \
    accv = __builtin_amdgcn_mfma_f32_16x16x32_bf16(xm, wm, accv, 0, 0, 0);         \
    accv = __builtin_amdgcn_mfma_f32_16x16x32_bf16(xh, wl, accv, 0, 0, 0);         \
    accv = __builtin_amdgcn_mfma_f32_16x16x32_bf16(xl, wh, accv, 0, 0, 0);

#define LDB(dst_h, dst_m, dst_l, nt)                                               \
    dst_h = *(const bf16x8*)(pb + (nt) * 512);                                     \
    dst_m = *(const bf16x8*)(pb + 65536 + (nt) * 512);                             \
    dst_l = *(const bf16x8*)(pb + 131072 + (nt) * 512);

// ---------------------------------------------------------------------------
// Kernel 1: MFMA gating GEMM + argmax + softmax + rank/hist + me accumulation.
// 128 tokens/block, 8 waves (512 thr): wave(g,h) = token-group g (32 tokens,
// 2 m-tiles) x K-half h (16 chunks). K-halves summed in LDS (2 barriers).
// 16 waves/CU = 4/SIMD for latency hiding; <=128 VGPR via per-nt B dbuf.
// ---------------------------------------------------------------------------
__global__ __launch_bounds__(512, 4) void gate_kernel(
    const float* __restrict__ x, const ushort* __restrict__ wgp,
    float* __restrict__ out, unsigned* __restrict__ packed_ws,
    int* __restrict__ hist_ws, float* __restrict__ me)
{
    __shared__ float lt[TB * 65];   // logits tile, stride 65
    __shared__ float inv[TB];

    const int tid = threadIdx.x;
    const int wv  = tid >> 6;
    const int l   = tid & 63;
    const int g   = wv & 3;          // token group (32 tokens)
    const int h   = wv >> 2;         // K half
    const int lr  = l & 15;          // fragment row (token) / col (expert)
    const int lg  = l >> 4;          // k-group within fragment

    const float* xa0 = x + (size_t)(blockIdx.x * TB + g * 32 + lr) * MD
                         + h * 512 + lg * 8;
    const float* xa1 = xa0 + 16 * MD;
    const ushort* wb = wgp + (size_t)l * 8 + (size_t)h * 16 * 2048;

    f32x4 acc[2][4];
#pragma unroll
    for (int mt = 0; mt < 2; ++mt)
#pragma unroll
        for (int nt = 0; nt < 4; ++nt) acc[mt][nt] = f32x4{0.f, 0.f, 0.f, 0.f};

    float4 a00 = *(const float4*)(xa0);
    float4 a01 = *(const float4*)(xa0 + 4);
    float4 a10 = *(const float4*)(xa1);
    float4 a11 = *(const float4*)(xa1 + 4);

    for (int c = 0; c < 16; ++c) {
        const ushort* pb = wb + c * 2048;
        // split current chunk's x (a-regs die here), then prefetch next chunk
        bf16x8 ah0, am0, al0, ah1, am1, al1;
        split8(a00, a01, ah0, am0, al0);
        split8(a10, a11, ah1, am1, al1);
        if (c < 15) {
            const float* xn0 = xa0 + (c + 1) * 32;
            const float* xn1 = xa1 + (c + 1) * 32;
            a00 = *(const float4*)(xn0);
            a01 = *(const float4*)(xn0 + 4);
            a10 = *(const float4*)(xn1);
            a11 = *(const float4*)(xn1 + 4);
        }
        // B: 1-deep double buffer across nt (24 VGPR instead of 48)
        bf16x8 bhA, bmA, blA, bhB, bmB, blB;
        LDB(bhA, bmA, blA, 0);
        LDB(bhB, bmB, blB, 1);
        MFMA6(acc[0][0], ah0, am0, al0, bhA, bmA, blA);
        MFMA6(acc[1][0], ah1, am1, al1, bhA, bmA, blA);
        LDB(bhA, bmA, blA, 2);
        MFMA6(acc[0][1], ah0, am0, al0, bhB, bmB, blB);
        MFMA6(acc[1][1], ah1, am1, al1, bhB, bmB, blB);
        LDB(bhB, bmB, blB, 3);
        MFMA6(acc[0][2], ah0, am0, al0, bhA, bmA, blA);
        MFMA6(acc[1][2], ah1, am1, al1, bhA, bmA, blA);
        MFMA6(acc[0][3], ah0, am0, al0, bhB, bmB, blB);
        MFMA6(acc[1][3], ah1, am1, al1, bhB, bmB, blB);
    }

    // ---- K-half reduction in LDS (C/D layout: col=lane&15, row=(lane>>4)*4+r)
    if (h == 0) {
#pragma unroll
        for (int mt = 0; mt < 2; ++mt)
#pragma unroll
            for (int nt = 0; nt < 4; ++nt)
#pragma unroll
                for (int r = 0; r < 4; ++r)
                    lt[(g * 32 + mt * 16 + lg * 4 + r) * 65 + nt * 16 + lr] =
                        acc[mt][nt][r];
    }
    __syncthreads();
    if (h == 1) {
#pragma unroll
        for (int mt = 0; mt < 2; ++mt)
#pragma unroll
            for (int nt = 0; nt < 4; ++nt)
#pragma unroll
                for (int r = 0; r < 4; ++r)
                    lt[(g * 32 + mt * 16 + lg * 4 + r) * 65 + nt * 16 + lr] +=
                        acc[mt][nt][r];
    }
    __syncthreads();

    // ---- epilogue: argmax / softmax / rank / hist (2 waves, 64 tokens each)
    if (tid < 128) {
        const int grp = tid >> 6;
        const int t   = tid & 63;
        float* row = &lt[(grp * 64 + t) * 65];
        float mx = -1e30f; int am = 0;
        for (int e = 0; e < NE; ++e) {
            float v = row[e];
            if (v > mx) { mx = v; am = e; }     // strict >: first-max argmax
        }
        float s = 0.f;
        for (int e = 0; e < NE; ++e) {
            float ev = __expf(row[e] - mx);
            row[e] = ev;
            s += ev;
        }
        float gv = 1.0f / s;
        const int gt = blockIdx.x * TB + grp * 64 + t;
        out[1 + gt] = (float)am;             // indices1_s
        out[2 + 2 * NT + gt] = gv;           // gates1_s (exp at max == 1)
        inv[grp * 64 + t] = gv;

        const unsigned long long below = (1ull << t) - 1ull;
        int rank = 0, mycnt = 0;
        for (int e = 0; e < NE; ++e) {
            unsigned long long msk = __ballot(am == e);
            if (t == e)  mycnt = (int)__popcll(msk);
            if (am == e) rank  = (int)__popcll(msk & below);
        }
        packed_ws[gt] = (unsigned)am | ((unsigned)rank << 8);
        hist_ws[(blockIdx.x * 2 + grp) * NE + t] = mycnt;
    }
    __syncthreads();

    if (tid < 128) {                       // me partial: 2 waves, 64 tokens each
        const int grp = tid >> 6;
        const int e   = tid & 63;
        const float* base = &lt[grp * 64 * 65];
        const float* iv   = &inv[grp * 64];
        float s = 0.f;
        for (int t = 0; t < 64; ++t) s += base[t * 65 + e] * iv[t];
        atomicAdd(&me[e], s);
    }
}

// ---------------------------------------------------------------------------
// Kernel 2: per-expert exclusive scan over the 1024 group histograms
// (in-place: hist_ws becomes group offsets). Also emits ce[e] = total.
// ---------------------------------------------------------------------------
__global__ __launch_bounds__(256) void scan_kernel(
    int* __restrict__ hist_ws, float* __restrict__ ce)
{
    const int e = blockIdx.x;
    const int tid = threadIdx.x;
    const int lane = tid & 63, wave = tid >> 6;
    __shared__ int wtot[4];

    int h[4];
#pragma unroll
    for (int j = 0; j < 4; ++j) h[j] = hist_ws[(tid * 4 + j) * NE + e];
    int s = h[0] + h[1] + h[2] + h[3];

    int scan = s;
#pragma unroll
    for (int d = 1; d < 64; d <<= 1) {
        int o = __shfl_up(scan, d, 64);
        if (lane >= d) scan += o;
    }
    if (lane == 63) wtot[wave] = scan;
    __syncthreads();
    int wpre = 0;
#pragma unroll
    for (int w = 0; w < 4; ++w)
        if (w < wave) wpre += wtot[w];

    int run = wpre + scan - s;
#pragma unroll
    for (int j = 0; j < 4; ++j) {
        hist_ws[(tid * 4 + j) * NE + e] = run;
        run += h[j];
    }
    if (tid == 255) ce[e] = (float)run;
}

// ---------------------------------------------------------------------------
// Kernel 3: locations1_s + (block 0) l_aux & scalar outputs.
// ---------------------------------------------------------------------------
__global__ __launch_bounds__(256) void emit_kernel(
    const unsigned* __restrict__ packed_ws, const int* __restrict__ offs_ws,
    const float* __restrict__ me, const float* __restrict__ ce,
    float* __restrict__ out)
{
    const int i = blockIdx.x * 256 + threadIdx.x;
    const unsigned p = packed_ws[i];
    const int am = (int)(p & 63u);
    const int rank = (int)(p >> 8);
    const int b = i >> 6;
    out[2 + NT + i] = (float)(offs_ws[b * NE + am] + rank);

    if (blockIdx.x == 0 && threadIdx.x < 64) {
        float v = me[threadIdx.x] * ce[threadIdx.x];
#pragma unroll
        for (int d = 32; d > 0; d >>= 1) v += __shfl_down(v, d, 64);
        if (threadIdx.x == 0) {
            out[0] = v * (float)((double)NE / ((double)NT * (double)NT));
            out[1 + NT] = 1024.0f;      // capacity = ceil(N/E) * 1.0
            out[2 + 3 * NT] = 64.0f;    // E
        }
    }
}

extern "C" void kernel_launch(void* const* d_in, const int* in_sizes, int n_in,
                              void* d_out, int out_size, void* d_ws, size_t ws_size,
                              hipStream_t stream)
{
    const float* x  = (const float*)d_in[0];
    const float* wg = (const float*)d_in[1];
    float* out = (float*)d_out;

    unsigned* packed_ws = (unsigned*)d_ws;                          // 256 KB
    int*      hist_ws   = (int*)((char*)d_ws + 262144);             // 256 KB
    float*    me        = (float*)((char*)d_ws + 524288);           // 256 B
    float*    ce        = (float*)((char*)d_ws + 524544);           // 256 B
    ushort*   wgp       = (ushort*)((char*)d_ws + 524800);          // 384 KB, 16B-aligned

    prep_kernel<<<32, 256, 0, stream>>>(wg, wgp, me);
    gate_kernel<<<NGATE, 512, 0, stream>>>(x, wgp, out, packed_ws, hist_ws, me);
    scan_kernel<<<NE, 256, 0, stream>>>(hist_ws, ce);
    emit_kernel<<<NT / 256, 256, 0, stream>>>(packed_ws, hist_ws, me, ce, out);
}

// Round 4
// 382.828 us; speedup vs baseline: 1.1046x; 1.0439x over previous
//
#include <hip/hip_runtime.h>

#define NT 65536
#define MD 1024
#define NE 64
#define TB 128                 // tokens per gate block (4 token-groups x 32)
#define NGATE (NT / TB)        // 512 gate blocks

typedef short bf16x8 __attribute__((ext_vector_type(8)));
typedef float f32x4  __attribute__((ext_vector_type(4)));

// Exact 3-way bf16 split: f == h + m + l (truncation split, zero error).
__device__ __forceinline__ void split1(float f, ushort& h, ushort& m, ushort& lo) {
    unsigned u  = __float_as_uint(f);
    unsigned hb = u & 0xFFFF0000u;
    float    r1 = f - __uint_as_float(hb);
    unsigned mb = __float_as_uint(r1) & 0xFFFF0000u;
    float    r2 = r1 - __uint_as_float(mb);       // <= 8 significant bits: exact bf16
    h  = (ushort)(hb >> 16);
    m  = (ushort)(mb >> 16);
    lo = (ushort)(__float_as_uint(r2) >> 16);
}

__device__ __forceinline__ void split8(const float4 a, const float4 b,
                                       bf16x8& h, bf16x8& m, bf16x8& lo) {
    float f[8] = {a.x, a.y, a.z, a.w, b.x, b.y, b.z, b.w};
#pragma unroll
    for (int j = 0; j < 8; ++j) {
        ushort hh, mm, ll;
        split1(f[j], hh, mm, ll);
        h[j] = (short)hh; m[j] = (short)mm; lo[j] = (short)ll;
    }
}

// ---------------------------------------------------------------------------
// Kernel 0: split wg into 3 bf16 planes laid out in MFMA-B-fragment order:
// wgp[s][c][nt][lane][j]  (s: split plane, c: k-chunk of 32, nt: 16-expert tile)
// elem idx = ((c*4+nt)*64 + lane)*8 + j, plane stride 65536 elements.
// Also zeroes me[] (replaces the hipMemsetAsync dispatch).
// ---------------------------------------------------------------------------
__global__ __launch_bounds__(256) void prep_kernel(
    const float* __restrict__ wg, ushort* __restrict__ wgp,
    float* __restrict__ me)
{
    const int idx = blockIdx.x * 256 + threadIdx.x;   // 0..8191
    if (blockIdx.x == 0 && threadIdx.x < NE) me[threadIdx.x] = 0.f;
    const int l  = idx & 63;
    const int nt = (idx >> 6) & 3;
    const int c  = idx >> 8;
    const int e  = nt * 16 + (l & 15);
    const int k0 = c * 32 + (l >> 4) * 8;
    const float* src = wg + (size_t)e * MD + k0;
    float4 a = *(const float4*)(src);
    float4 b = *(const float4*)(src + 4);
    bf16x8 h, m, lo;
    split8(a, b, h, m, lo);
    *(bf16x8*)(wgp + (size_t)idx * 8)          = h;
    *(bf16x8*)(wgp + 65536 + (size_t)idx * 8)  = m;
    *(bf16x8*)(wgp + 131072 + (size_t)idx * 8) = lo;
}

// 6-product split-bf16 MFMA accumulate (drops only ml/lm/ll ~2^-23 terms)
#define MFMA6(accv, xh, xm, xl, wh, wm, wl)                                        \
    accv = __builtin_amdgcn_mfma_f32_16x16x32_bf16(xh, wh, accv, 0, 0, 0);         \
    accv = __builtin_amdgcn_mfma_f32_16x16x32_bf16(xh, wm, accv, 0, 0, 0);         \
    accv = __builtin_amdgcn_mfma_f32_16x16x32_bf16(xm, wh, accv, 0, 0, 0);         \
    accv = __builtin_amdgcn_mfma_f32_16x16x32_bf16(xm, wm, accv, 0, 0, 0);         \
    accv = __builtin_amdgcn_mfma_f32_16x16x32_bf16(xh, wl, accv, 0, 0, 0);         \
    accv = __builtin_amdgcn_mfma_f32_16x16x32_bf16(xl, wh, accv, 0, 0, 0);

// ---------------------------------------------------------------------------
// Kernel 1: MFMA gating GEMM + argmax + softmax + rank/hist + me accumulation.
// 128 tokens/block, 8 waves (512 thr): wave(g,h) = token-group g (32 tokens,
// 2 m-tiles) x K-half h (16 chunks). K-halves summed in LDS (2 barriers).
//
// B fragments staged L2 -> LDS once per block (24 KB / K-step, reg-staged,
// double-buffered, 1 barrier/step): B L2 traffic 786 MB -> 196 MB so the
// x HBM stream runs uncontended. B LDS buffer (48 KB) is UNIONED with the
// epilogue logits tile (33 KB) -- disjoint lifetimes across the final barrier.
// 16 waves/CU = 4/SIMD; ~115 VGPR.
// ---------------------------------------------------------------------------
__global__ __launch_bounds__(512, 4) void gate_kernel(
    const float* __restrict__ x, const ushort* __restrict__ wgp,
    float* __restrict__ out, unsigned* __restrict__ packed_ws,
    int* __restrict__ hist_ws, float* __restrict__ me)
{
    // union: K-loop B buffers (2 parity x 2 h x 12 frag x 1 KB = 48 KB)
    //        epilogue logits tile lt[128][65] (33.3 KB)
    __shared__ __align__(16) float uni[12288];
    __shared__ float inv[TB];
    ushort* bsm = (ushort*)uni;
    float*  lt  = uni;

    const int tid = threadIdx.x;
    const int wv  = tid >> 6;
    const int l   = tid & 63;
    const int g   = wv & 3;          // token group (32 tokens)
    const int h   = wv >> 2;         // K half
    const int lr  = l & 15;          // fragment row (token) / col (expert)
    const int lg  = l >> 4;          // k-group within fragment

    const float* xa0 = x + (size_t)(blockIdx.x * TB + g * 32 + lr) * MD
                         + h * 512 + lg * 8;
    const float* xa1 = xa0 + 16 * MD;

    // staging assignment: 24 x 1KB fragment blocks per K-step, 3 per wave
    const int id0 = wv * 3;
    const int h0 = id0 / 12,       f0 = id0 % 12;
    const int h1 = (id0 + 1) / 12, f1 = (id0 + 1) % 12;
    const int h2 = (id0 + 2) / 12, f2 = (id0 + 2) % 12;
    const ushort* gs0 = wgp + (f0 >> 2) * 65536 + ((h0 * 16) * 4 + (f0 & 3)) * 512 + l * 8;
    const ushort* gs1 = wgp + (f1 >> 2) * 65536 + ((h1 * 16) * 4 + (f1 & 3)) * 512 + l * 8;
    const ushort* gs2 = wgp + (f2 >> 2) * 65536 + ((h2 * 16) * 4 + (f2 & 3)) * 512 + l * 8;
    // global stride per K-step: one chunk = 4 fragments = 2048 ushorts

    f32x4 acc[2][4];
#pragma unroll
    for (int mt = 0; mt < 2; ++mt)
#pragma unroll
        for (int nt = 0; nt < 4; ++nt) acc[mt][nt] = f32x4{0.f, 0.f, 0.f, 0.f};

    // prologue: stage step 0 into parity-0 buffers
    {
        float4 v0 = *(const float4*)(gs0);
        float4 v1 = *(const float4*)(gs1);
        float4 v2 = *(const float4*)(gs2);
        *(float4*)(bsm + ((0 * 2 + h0) * 12 + f0) * 512 + l * 8) = v0;
        *(float4*)(bsm + ((0 * 2 + h1) * 12 + f1) * 512 + l * 8) = v1;
        *(float4*)(bsm + ((0 * 2 + h2) * 12 + f2) * 512 + l * 8) = v2;
    }

    float4 a00 = *(const float4*)(xa0);
    float4 a01 = *(const float4*)(xa0 + 4);
    float4 a10 = *(const float4*)(xa1);
    float4 a11 = *(const float4*)(xa1 + 4);
    __syncthreads();

    for (int s = 0; s < 16; ++s) {
        const int p = s & 1;
        // issue next step's B stage loads early (latency hides under MFMAs)
        float4 sv0, sv1, sv2;
        if (s < 15) {
            sv0 = *(const float4*)(gs0 + (s + 1) * 2048);
            sv1 = *(const float4*)(gs1 + (s + 1) * 2048);
            sv2 = *(const float4*)(gs2 + (s + 1) * 2048);
        }
        // split current chunk's x, then prefetch next chunk's x
        bf16x8 ah0, am0, al0, ah1, am1, al1;
        split8(a00, a01, ah0, am0, al0);
        split8(a10, a11, ah1, am1, al1);
        if (s < 15) {
            const float* xn0 = xa0 + (s + 1) * 32;
            const float* xn1 = xa1 + (s + 1) * 32;
            a00 = *(const float4*)(xn0);
            a01 = *(const float4*)(xn0 + 4);
            a10 = *(const float4*)(xn1);
            a11 = *(const float4*)(xn1 + 4);
        }
        // MFMAs: B fragments from LDS (lane-linear ds_read_b128)
        const ushort* pb = bsm + (p * 2 + h) * 6144 + l * 8;
#pragma unroll
        for (int nt = 0; nt < 4; ++nt) {
            bf16x8 bh = *(const bf16x8*)(pb + (0 + nt) * 512);
            bf16x8 bm = *(const bf16x8*)(pb + (4 + nt) * 512);
            bf16x8 bl = *(const bf16x8*)(pb + (8 + nt) * 512);
            MFMA6(acc[0][nt], ah0, am0, al0, bh, bm, bl);
            MFMA6(acc[1][nt], ah1, am1, al1, bh, bm, bl);
        }
        // write staged fragments into the other parity
        if (s < 15) {
            const int q = p ^ 1;
            *(float4*)(bsm + ((q * 2 + h0) * 12 + f0) * 512 + l * 8) = sv0;
            *(float4*)(bsm + ((q * 2 + h1) * 12 + f1) * 512 + l * 8) = sv1;
            *(float4*)(bsm + ((q * 2 + h2) * 12 + f2) * 512 + l * 8) = sv2;
        }
        __syncthreads();
    }

    // ---- K-half reduction in LDS (C/D layout: col=lane&15, row=(lane>>4)*4+r)
    // (B buffers dead from here; lt aliases them -- final barrier above fences)
    if (h == 0) {
#pragma unroll
        for (int mt = 0; mt < 2; ++mt)
#pragma unroll
            for (int nt = 0; nt < 4; ++nt)
#pragma unroll
                for (int r = 0; r < 4; ++r)
                    lt[(g * 32 + mt * 16 + lg * 4 + r) * 65 + nt * 16 + lr] =
                        acc[mt][nt][r];
    }
    __syncthreads();
    if (h == 1) {
#pragma unroll
        for (int mt = 0; mt < 2; ++mt)
#pragma unroll
            for (int nt = 0; nt < 4; ++nt)
#pragma unroll
                for (int r = 0; r < 4; ++r)
                    lt[(g * 32 + mt * 16 + lg * 4 + r) * 65 + nt * 16 + lr] +=
                        acc[mt][nt][r];
    }
    __syncthreads();

    // ---- epilogue: argmax / softmax / rank / hist (2 waves, 64 tokens each)
    if (tid < 128) {
        const int grp = tid >> 6;
        const int t   = tid & 63;
        float* row = &lt[(grp * 64 + t) * 65];
        float mx = -1e30f; int am = 0;
        for (int e = 0; e < NE; ++e) {
            float v = row[e];
            if (v > mx) { mx = v; am = e; }     // strict >: first-max argmax
        }
        float sum = 0.f;
        for (int e = 0; e < NE; ++e) {
            float ev = __expf(row[e] - mx);
            row[e] = ev;
            sum += ev;
        }
        float gv = 1.0f / sum;
        const int gt = blockIdx.x * TB + grp * 64 + t;
        out[1 + gt] = (float)am;             // indices1_s
        out[2 + 2 * NT + gt] = gv;           // gates1_s (exp at max == 1)
        inv[grp * 64 + t] = gv;

        const unsigned long long below = (1ull << t) - 1ull;
        int rank = 0, mycnt = 0;
        for (int e = 0; e < NE; ++e) {
            unsigned long long msk = __ballot(am == e);
            if (t == e)  mycnt = (int)__popcll(msk);
            if (am == e) rank  = (int)__popcll(msk & below);
        }
        packed_ws[gt] = (unsigned)am | ((unsigned)rank << 8);
        hist_ws[(blockIdx.x * 2 + grp) * NE + t] = mycnt;
    }
    __syncthreads();

    if (tid < 128) {                       // me partial: 2 waves, 64 tokens each
        const int grp = tid >> 6;
        const int e   = tid & 63;
        const float* base = &lt[grp * 64 * 65];
        const float* iv   = &inv[grp * 64];
        float s = 0.f;
        for (int t = 0; t < 64; ++t) s += base[t * 65 + e] * iv[t];
        atomicAdd(&me[e], s);
    }
}

// ---------------------------------------------------------------------------
// Kernel 2: per-expert exclusive scan over the 1024 group histograms
// (in-place: hist_ws becomes group offsets). Also emits ce[e] = total.
// ---------------------------------------------------------------------------
__global__ __launch_bounds__(256) void scan_kernel(
    int* __restrict__ hist_ws, float* __restrict__ ce)
{
    const int e = blockIdx.x;
    const int tid = threadIdx.x;
    const int lane = tid & 63, wave = tid >> 6;
    __shared__ int wtot[4];

    int h[4];
#pragma unroll
    for (int j = 0; j < 4; ++j) h[j] = hist_ws[(tid * 4 + j) * NE + e];
    int s = h[0] + h[1] + h[2] + h[3];

    int scan = s;
#pragma unroll
    for (int d = 1; d < 64; d <<= 1) {
        int o = __shfl_up(scan, d, 64);
        if (lane >= d) scan += o;
    }
    if (lane == 63) wtot[wave] = scan;
    __syncthreads();
    int wpre = 0;
#pragma unroll
    for (int w = 0; w < 4; ++w)
        if (w < wave) wpre += wtot[w];

    int run = wpre + scan - s;
#pragma unroll
    for (int j = 0; j < 4; ++j) {
        hist_ws[(tid * 4 + j) * NE + e] = run;
        run += h[j];
    }
    if (tid == 255) ce[e] = (float)run;
}

// ---------------------------------------------------------------------------
// Kernel 3: locations1_s + (block 0) l_aux & scalar outputs.
// ---------------------------------------------------------------------------
__global__ __launch_bounds__(256) void emit_kernel(
    const unsigned* __restrict__ packed_ws, const int* __restrict__ offs_ws,
    const float* __restrict__ me, const float* __restrict__ ce,
    float* __restrict__ out)
{
    const int i = blockIdx.x * 256 + threadIdx.x;
    const unsigned p = packed_ws[i];
    const int am = (int)(p & 63u);
    const int rank = (int)(p >> 8);
    const int b = i >> 6;
    out[2 + NT + i] = (float)(offs_ws[b * NE + am] + rank);

    if (blockIdx.x == 0 && threadIdx.x < 64) {
        float v = me[threadIdx.x] * ce[threadIdx.x];
#pragma unroll
        for (int d = 32; d > 0; d >>= 1) v += __shfl_down(v, d, 64);
        if (threadIdx.x == 0) {
            out[0] = v * (float)((double)NE / ((double)NT * (double)NT));
            out[1 + NT] = 1024.0f;      // capacity = ceil(N/E) * 1.0
            out[2 + 3 * NT] = 64.0f;    // E
        }
    }
}

extern "C" void kernel_launch(void* const* d_in, const int* in_sizes, int n_in,
                              void* d_out, int out_size, void* d_ws, size_t ws_size,
                              hipStream_t stream)
{
    const float* x  = (const float*)d_in[0];
    const float* wg = (const float*)d_in[1];
    float* out = (float*)d_out;

    unsigned* packed_ws = (unsigned*)d_ws;                          // 256 KB
    int*      hist_ws   = (int*)((char*)d_ws + 262144);             // 256 KB
    float*    me        = (float*)((char*)d_ws + 524288);           // 256 B
    float*    ce        = (float*)((char*)d_ws + 524544);           // 256 B
    ushort*   wgp       = (ushort*)((char*)d_ws + 524800);          // 384 KB, 16B-aligned

    prep_kernel<<<32, 256, 0, stream>>>(wg, wgp, me);
    gate_kernel<<<NGATE, 512, 0, stream>>>(x, wgp, out, packed_ws, hist_ws, me);
    scan_kernel<<<NE, 256, 0, stream>>>(hist_ws, ce);
    emit_kernel<<<NT / 256, 256, 0, stream>>>(packed_ws, hist_ws, me, ce, out);
}

// Round 5
// 382.408 us; speedup vs baseline: 1.1058x; 1.0011x over previous
//
#include <hip/hip_runtime.h>

#define NT 65536
#define MD 1024
#define NE 64
#define TB 128                 // tokens per gate block (4 token-groups x 32)
#define NGATE (NT / TB)        // 512 gate blocks

typedef short bf16x8 __attribute__((ext_vector_type(8)));
typedef float f32x4  __attribute__((ext_vector_type(4)));

// Exact 3-way bf16 split: f == h + m + l (truncation split, zero error).
__device__ __forceinline__ void split1(float f, ushort& h, ushort& m, ushort& lo) {
    unsigned u  = __float_as_uint(f);
    unsigned hb = u & 0xFFFF0000u;
    float    r1 = f - __uint_as_float(hb);
    unsigned mb = __float_as_uint(r1) & 0xFFFF0000u;
    float    r2 = r1 - __uint_as_float(mb);       // <= 8 significant bits: exact bf16
    h  = (ushort)(hb >> 16);
    m  = (ushort)(mb >> 16);
    lo = (ushort)(__float_as_uint(r2) >> 16);
}

__device__ __forceinline__ void split8(const float4 a, const float4 b,
                                       bf16x8& h, bf16x8& m, bf16x8& lo) {
    float f[8] = {a.x, a.y, a.z, a.w, b.x, b.y, b.z, b.w};
#pragma unroll
    for (int j = 0; j < 8; ++j) {
        ushort hh, mm, ll;
        split1(f[j], hh, mm, ll);
        h[j] = (short)hh; m[j] = (short)mm; lo[j] = (short)ll;
    }
}

// ---------------------------------------------------------------------------
// Kernel 0: split wg into 3 bf16 planes laid out in MFMA-B-fragment order:
// wgp[s][c][nt][lane][j]  (s: split plane, c: k-chunk of 32, nt: 16-expert tile)
// elem idx = ((c*4+nt)*64 + lane)*8 + j, plane stride 65536 elements.
// ---------------------------------------------------------------------------
__global__ __launch_bounds__(256) void prep_kernel(
    const float* __restrict__ wg, ushort* __restrict__ wgp)
{
    const int idx = blockIdx.x * 256 + threadIdx.x;   // 0..8191
    const int l  = idx & 63;
    const int nt = (idx >> 6) & 3;
    const int c  = idx >> 8;
    const int e  = nt * 16 + (l & 15);
    const int k0 = c * 32 + (l >> 4) * 8;
    const float* src = wg + (size_t)e * MD + k0;
    float4 a = *(const float4*)(src);
    float4 b = *(const float4*)(src + 4);
    bf16x8 h, m, lo;
    split8(a, b, h, m, lo);
    *(bf16x8*)(wgp + (size_t)idx * 8)          = h;
    *(bf16x8*)(wgp + 65536 + (size_t)idx * 8)  = m;
    *(bf16x8*)(wgp + 131072 + (size_t)idx * 8) = lo;
}

// 6-product split-bf16 MFMA accumulate (drops only ml/lm/ll ~2^-23 terms)
#define MFMA6(accv, xh, xm, xl, wh, wm, wl)                                        \
    accv = __builtin_amdgcn_mfma_f32_16x16x32_bf16(xh, wh, accv, 0, 0, 0);         \
    accv = __builtin_amdgcn_mfma_f32_16x16x32_bf16(xh, wm, accv, 0, 0, 0);         \
    accv = __builtin_amdgcn_mfma_f32_16x16x32_bf16(xm, wh, accv, 0, 0, 0);         \
    accv = __builtin_amdgcn_mfma_f32_16x16x32_bf16(xm, wm, accv, 0, 0, 0);         \
    accv = __builtin_amdgcn_mfma_f32_16x16x32_bf16(xh, wl, accv, 0, 0, 0);         \
    accv = __builtin_amdgcn_mfma_f32_16x16x32_bf16(xl, wh, accv, 0, 0, 0);

// ---------------------------------------------------------------------------
// Kernel 1: MFMA gating GEMM + argmax + softmax + rank/hist + me partials.
// K-loop identical to the round-4 kernel (B staged L2->LDS, double-buffered,
// 1 barrier/step). Epilogue now uses all 8 waves; me via per-block partials
// (NO global atomics; reduced in scan_kernel).
// ---------------------------------------------------------------------------
__global__ __launch_bounds__(512, 4) void gate_kernel(
    const float* __restrict__ x, const ushort* __restrict__ wgp,
    float* __restrict__ out, unsigned* __restrict__ packed_ws,
    int* __restrict__ hist_ws, float* __restrict__ me_part)
{
    // union: K-loop B buffers (2 parity x 2 h x 12 frag x 1 KB = 48 KB)
    //        epilogue logits tile lt[128][65] (33.3 KB)
    __shared__ __align__(16) float uni[12288];
    __shared__ float inv[TB];
    __shared__ int   amL[TB];
    __shared__ float sme[8][NE];
    ushort* bsm = (ushort*)uni;
    float*  lt  = uni;

    const int tid = threadIdx.x;
    const int wv  = tid >> 6;
    const int l   = tid & 63;
    const int g   = wv & 3;          // token group (32 tokens)
    const int h   = wv >> 2;         // K half
    const int lr  = l & 15;          // fragment row (token) / col (expert)
    const int lg  = l >> 4;          // k-group within fragment

    const float* xa0 = x + (size_t)(blockIdx.x * TB + g * 32 + lr) * MD
                         + h * 512 + lg * 8;
    const float* xa1 = xa0 + 16 * MD;

    // staging assignment: 24 x 1KB fragment blocks per K-step, 3 per wave
    const int id0 = wv * 3;
    const int h0 = id0 / 12,       f0 = id0 % 12;
    const int h1 = (id0 + 1) / 12, f1 = (id0 + 1) % 12;
    const int h2 = (id0 + 2) / 12, f2 = (id0 + 2) % 12;
    const ushort* gs0 = wgp + (f0 >> 2) * 65536 + ((h0 * 16) * 4 + (f0 & 3)) * 512 + l * 8;
    const ushort* gs1 = wgp + (f1 >> 2) * 65536 + ((h1 * 16) * 4 + (f1 & 3)) * 512 + l * 8;
    const ushort* gs2 = wgp + (f2 >> 2) * 65536 + ((h2 * 16) * 4 + (f2 & 3)) * 512 + l * 8;

    f32x4 acc[2][4];
#pragma unroll
    for (int mt = 0; mt < 2; ++mt)
#pragma unroll
        for (int nt = 0; nt < 4; ++nt) acc[mt][nt] = f32x4{0.f, 0.f, 0.f, 0.f};

    // prologue: stage step 0 into parity-0 buffers
    {
        float4 v0 = *(const float4*)(gs0);
        float4 v1 = *(const float4*)(gs1);
        float4 v2 = *(const float4*)(gs2);
        *(float4*)(bsm + ((0 * 2 + h0) * 12 + f0) * 512 + l * 8) = v0;
        *(float4*)(bsm + ((0 * 2 + h1) * 12 + f1) * 512 + l * 8) = v1;
        *(float4*)(bsm + ((0 * 2 + h2) * 12 + f2) * 512 + l * 8) = v2;
    }

    float4 a00 = *(const float4*)(xa0);
    float4 a01 = *(const float4*)(xa0 + 4);
    float4 a10 = *(const float4*)(xa1);
    float4 a11 = *(const float4*)(xa1 + 4);
    __syncthreads();

    for (int s = 0; s < 16; ++s) {
        const int p = s & 1;
        // issue next step's B stage loads early (latency hides under MFMAs)
        float4 sv0, sv1, sv2;
        if (s < 15) {
            sv0 = *(const float4*)(gs0 + (s + 1) * 2048);
            sv1 = *(const float4*)(gs1 + (s + 1) * 2048);
            sv2 = *(const float4*)(gs2 + (s + 1) * 2048);
        }
        // split current chunk's x, then prefetch next chunk's x
        bf16x8 ah0, am0, al0, ah1, am1, al1;
        split8(a00, a01, ah0, am0, al0);
        split8(a10, a11, ah1, am1, al1);
        if (s < 15) {
            const float* xn0 = xa0 + (s + 1) * 32;
            const float* xn1 = xa1 + (s + 1) * 32;
            a00 = *(const float4*)(xn0);
            a01 = *(const float4*)(xn0 + 4);
            a10 = *(const float4*)(xn1);
            a11 = *(const float4*)(xn1 + 4);
        }
        // MFMAs: B fragments from LDS (lane-linear ds_read_b128)
        const ushort* pb = bsm + (p * 2 + h) * 6144 + l * 8;
#pragma unroll
        for (int nt = 0; nt < 4; ++nt) {
            bf16x8 bh = *(const bf16x8*)(pb + (0 + nt) * 512);
            bf16x8 bm = *(const bf16x8*)(pb + (4 + nt) * 512);
            bf16x8 bl = *(const bf16x8*)(pb + (8 + nt) * 512);
            MFMA6(acc[0][nt], ah0, am0, al0, bh, bm, bl);
            MFMA6(acc[1][nt], ah1, am1, al1, bh, bm, bl);
        }
        // write staged fragments into the other parity
        if (s < 15) {
            const int q = p ^ 1;
            *(float4*)(bsm + ((q * 2 + h0) * 12 + f0) * 512 + l * 8) = sv0;
            *(float4*)(bsm + ((q * 2 + h1) * 12 + f1) * 512 + l * 8) = sv1;
            *(float4*)(bsm + ((q * 2 + h2) * 12 + f2) * 512 + l * 8) = sv2;
        }
        __syncthreads();
    }

    // ---- K-half reduction in LDS (C/D layout: col=lane&15, row=(lane>>4)*4+r)
    if (h == 0) {
#pragma unroll
        for (int mt = 0; mt < 2; ++mt)
#pragma unroll
            for (int nt = 0; nt < 4; ++nt)
#pragma unroll
                for (int r = 0; r < 4; ++r)
                    lt[(g * 32 + mt * 16 + lg * 4 + r) * 65 + nt * 16 + lr] =
                        acc[mt][nt][r];
    }
    __syncthreads();
    if (h == 1) {
#pragma unroll
        for (int mt = 0; mt < 2; ++mt)
#pragma unroll
            for (int nt = 0; nt < 4; ++nt)
#pragma unroll
                for (int r = 0; r < 4; ++r)
                    lt[(g * 32 + mt * 16 + lg * 4 + r) * 65 + nt * 16 + lr] +=
                        acc[mt][nt][r];
    }
    __syncthreads();

    // ---- (a) argmax + softmax: 4 lanes per token (16-expert slices) ----
    {
        const int t = tid >> 2;          // token 0..127
        const int q = tid & 3;           // expert quarter
        float* row = &lt[t * 65 + q * 16];
        float mx = -1e30f; int am = 0;
#pragma unroll
        for (int j = 0; j < 16; ++j) {
            float v = row[j];
            if (v > mx) { mx = v; am = q * 16 + j; }   // strict >: first-max
        }
#pragma unroll
        for (int d = 1; d < 4; d <<= 1) {              // combine, tie -> lower idx
            float om = __shfl_xor(mx, d, 64);
            int   oa = __shfl_xor(am, d, 64);
            if (om > mx || (om == mx && oa < am)) { mx = om; am = oa; }
        }
        float s = 0.f;
#pragma unroll
        for (int j = 0; j < 16; ++j) {
            float ev = __expf(row[j] - mx);
            row[j] = ev;
            s += ev;
        }
#pragma unroll
        for (int d = 1; d < 4; d <<= 1) s += __shfl_xor(s, d, 64);
        if (q == 0) {
            float gv = 1.0f / s;
            const int gt = blockIdx.x * TB + t;
            out[1 + gt] = (float)am;           // indices1_s
            out[2 + 2 * NT + gt] = gv;         // gates1_s (exp at max == 1)
            inv[t] = gv;
            amL[t] = am;
        }
    }
    __syncthreads();

    // ---- (b) rank/hist: 8 waves, 16 experts each ----
    {
        const int grp = wv >> 2;             // 64-token group
        const int e0  = (wv & 3) * 16;
        const int t   = l;
        const int amv = amL[grp * 64 + t];
        const unsigned long long below = (1ull << t) - 1ull;
        const int gt = blockIdx.x * TB + grp * 64 + t;
#pragma unroll
        for (int j = 0; j < 16; ++j) {
            const int e = e0 + j;
            unsigned long long msk = __ballot(amv == e);
            if (t == e)
                hist_ws[(blockIdx.x * 2 + grp) * NE + e] = (int)__popcll(msk);
            if (amv == e)
                packed_ws[gt] = (unsigned)amv | ((unsigned)__popcll(msk & below) << 8);
        }
    }

    // ---- (c) me partials: 512 threads x 16 tokens, then 64-wide combine ----
    {
        const int e  = tid & 63;
        const int q8 = tid >> 6;
        float s = 0.f;
#pragma unroll
        for (int j = 0; j < 16; ++j) {
            const int t = q8 * 16 + j;
            s += lt[t * 65 + e] * inv[t];
        }
        sme[q8][e] = s;
    }
    __syncthreads();
    if (tid < NE) {
        float s = 0.f;
#pragma unroll
        for (int q8 = 0; q8 < 8; ++q8) s += sme[q8][tid];
        me_part[blockIdx.x * NE + tid] = s;    // one coalesced write, no atomics
    }
}

// ---------------------------------------------------------------------------
// Kernel 2: per-expert exclusive scan over the 1024 group histograms
// (in-place: hist_ws becomes group offsets). Emits ce[e] = total and
// me[e] = sum of gate-block partials (contention-free me reduction).
// ---------------------------------------------------------------------------
__global__ __launch_bounds__(256) void scan_kernel(
    int* __restrict__ hist_ws, const float* __restrict__ me_part,
    float* __restrict__ me, float* __restrict__ ce)
{
    const int e = blockIdx.x;
    const int tid = threadIdx.x;
    const int lane = tid & 63, wave = tid >> 6;
    __shared__ int wtot[4];
    __shared__ float wsum[4];

    int h[4];
#pragma unroll
    for (int j = 0; j < 4; ++j) h[j] = hist_ws[(tid * 4 + j) * NE + e];
    int s = h[0] + h[1] + h[2] + h[3];

    // me partial reduction (512 gate blocks, 2 per thread)
    float ms = me_part[(size_t)(2 * tid) * NE + e]
             + me_part[(size_t)(2 * tid + 1) * NE + e];
#pragma unroll
    for (int d = 32; d > 0; d >>= 1) ms += __shfl_down(ms, d, 64);
    if (lane == 0) wsum[wave] = ms;

    int scan = s;
#pragma unroll
    for (int d = 1; d < 64; d <<= 1) {
        int o = __shfl_up(scan, d, 64);
        if (lane >= d) scan += o;
    }
    if (lane == 63) wtot[wave] = scan;
    __syncthreads();
    int wpre = 0;
#pragma unroll
    for (int w = 0; w < 4; ++w)
        if (w < wave) wpre += wtot[w];

    int run = wpre + scan - s;
#pragma unroll
    for (int j = 0; j < 4; ++j) {
        hist_ws[(tid * 4 + j) * NE + e] = run;
        run += h[j];
    }
    if (tid == 0) me[e] = wsum[0] + wsum[1] + wsum[2] + wsum[3];
    if (tid == 255) ce[e] = (float)run;
}

// ---------------------------------------------------------------------------
// Kernel 3: locations1_s + (block 0) l_aux & scalar outputs.
// ---------------------------------------------------------------------------
__global__ __launch_bounds__(256) void emit_kernel(
    const unsigned* __restrict__ packed_ws, const int* __restrict__ offs_ws,
    const float* __restrict__ me, const float* __restrict__ ce,
    float* __restrict__ out)
{
    const int i = blockIdx.x * 256 + threadIdx.x;
    const unsigned p = packed_ws[i];
    const int am = (int)(p & 63u);
    const int rank = (int)(p >> 8);
    const int b = i >> 6;
    out[2 + NT + i] = (float)(offs_ws[b * NE + am] + rank);

    if (blockIdx.x == 0 && threadIdx.x < 64) {
        float v = me[threadIdx.x] * ce[threadIdx.x];
#pragma unroll
        for (int d = 32; d > 0; d >>= 1) v += __shfl_down(v, d, 64);
        if (threadIdx.x == 0) {
            out[0] = v * (float)((double)NE / ((double)NT * (double)NT));
            out[1 + NT] = 1024.0f;      // capacity = ceil(N/E) * 1.0
            out[2 + 3 * NT] = 64.0f;    // E
        }
    }
}

extern "C" void kernel_launch(void* const* d_in, const int* in_sizes, int n_in,
                              void* d_out, int out_size, void* d_ws, size_t ws_size,
                              hipStream_t stream)
{
    const float* x  = (const float*)d_in[0];
    const float* wg = (const float*)d_in[1];
    float* out = (float*)d_out;

    unsigned* packed_ws = (unsigned*)d_ws;                          // 256 KB @ 0
    int*      hist_ws   = (int*)((char*)d_ws + 262144);             // 256 KB
    float*    me_part   = (float*)((char*)d_ws + 524288);           // 128 KB
    float*    me        = (float*)((char*)d_ws + 655360);           // 256 B
    float*    ce        = (float*)((char*)d_ws + 655616);           // 256 B
    ushort*   wgp       = (ushort*)((char*)d_ws + 655872);          // 384 KB, 16B-aligned

    prep_kernel<<<32, 256, 0, stream>>>(wg, wgp);
    gate_kernel<<<NGATE, 512, 0, stream>>>(x, wgp, out, packed_ws, hist_ws, me_part);
    scan_kernel<<<NE, 256, 0, stream>>>(hist_ws, me_part, me, ce);
    emit_kernel<<<NT / 256, 256, 0, stream>>>(packed_ws, hist_ws, me, ce, out);
}